// Round 8
// baseline (358.998 us; speedup 1.0000x reference)
//
#include <hip/hip_runtime.h>

#define N_NODES 100000
#define EMB 64
#define N_EDGES 1280000
#define SCAN_TILE 1024   // nodes per scan block (256 threads x 4)
#define NPART 8          // node partitions == XCD count (blockIdx%8 affinity heuristic)
#define PART_NODES 12500 // N_NODES / NPART
#define FILL_EPB 1024    // edges per fill block (256 threads x 4)

typedef unsigned long long u64;
typedef _Float16 f16;

// ---- degree count over destinations, 4 edges/thread; NT edge reads ----
__global__ void deg_kernel(const int* __restrict__ dst, int* __restrict__ deg) {
    int t = blockIdx.x * blockDim.x + threadIdx.x;
    int e = t * 4;
    if (e + 3 < N_EDGES) {
        u64 lo = __builtin_nontemporal_load((const u64*)(dst + e));
        u64 hi = __builtin_nontemporal_load((const u64*)(dst + e) + 1);
        atomicAdd(&deg[(unsigned)(lo & 0xffffffffu)], 1);
        atomicAdd(&deg[(unsigned)(lo >> 32)], 1);
        atomicAdd(&deg[(unsigned)(hi & 0xffffffffu)], 1);
        atomicAdd(&deg[(unsigned)(hi >> 32)], 1);
    }
}

// ---- dinv = deg^-0.5, rdinv = deg^0.5 (both 0 where deg==0) ----
__global__ void norm_kernel(const int* __restrict__ deg, float* __restrict__ dinv,
                            float* __restrict__ rdinv) {
    int i = blockIdx.x * blockDim.x + threadIdx.x;
    if (i < N_NODES) {
        int d = deg[i];
        float fd = (float)d;
        dinv[i]  = (d > 0) ? rsqrtf(fd) : 0.0f;
        rdinv[i] = (d > 0) ? sqrtf(fd) : 0.0f;
    }
}

// ---- y0 = dinv * emb, fp16, 4 elems/thread (all 4 in same node row) ----
__global__ void y0_kernel(const float* __restrict__ emb, const float* __restrict__ dinv,
                          f16* __restrict__ y0) {
    int i = blockIdx.x * blockDim.x + threadIdx.x;
    const int n4 = N_NODES * EMB / 4;
    if (i < n4) {
        float dv = dinv[i >> 4];  // 16 float4s per 64-dim row
        float4 v = ((const float4*)emb)[i];
        f16 h[4] = {(f16)(v.x * dv), (f16)(v.y * dv), (f16)(v.z * dv), (f16)(v.w * dv)};
        ((u64*)y0)[i] = *(const u64*)h;
    }
}

// ---- scan pass 1: per-block local exclusive scan + block sums ----
__global__ void scan1_kernel(const int* __restrict__ deg, int* __restrict__ local_scan,
                             int* __restrict__ block_sums) {
    __shared__ int lds[256];
    int base = blockIdx.x * SCAN_TILE;
    int vals[4];
    int tsum = 0;
#pragma unroll
    for (int k = 0; k < 4; ++k) {
        int i = base + threadIdx.x * 4 + k;
        vals[k] = (i < N_NODES) ? deg[i] : 0;
        tsum += vals[k];
    }
    lds[threadIdx.x] = tsum;
    __syncthreads();
    for (int off = 1; off < 256; off <<= 1) {
        int v = (threadIdx.x >= (unsigned)off) ? lds[threadIdx.x - off] : 0;
        __syncthreads();
        lds[threadIdx.x] += v;
        __syncthreads();
    }
    int texcl = lds[threadIdx.x] - tsum;
    if (threadIdx.x == 255) block_sums[blockIdx.x] = lds[255];
    int run = texcl;
#pragma unroll
    for (int k = 0; k < 4; ++k) {
        int i = base + threadIdx.x * 4 + k;
        if (i < N_NODES) local_scan[i] = run;
        run += vals[k];
    }
}

// ---- scan pass 2: exclusive scan of the 98 block sums (single block) ----
__global__ void scan2_kernel(int* __restrict__ block_sums, int nb) {
    __shared__ int lds[128];
    int v = (threadIdx.x < (unsigned)nb) ? block_sums[threadIdx.x] : 0;
    lds[threadIdx.x] = v;
    __syncthreads();
    for (int off = 1; off < 128; off <<= 1) {
        int t = (threadIdx.x >= (unsigned)off) ? lds[threadIdx.x - off] : 0;
        __syncthreads();
        lds[threadIdx.x] += t;
        __syncthreads();
    }
    if (threadIdx.x < (unsigned)nb) block_sums[threadIdx.x] = lds[threadIdx.x] - v;
}

// ---- scan pass 3: add block offsets; init cursor; cap row_start ----
__global__ void scan3_kernel(int* __restrict__ row_start, const int* __restrict__ block_sums,
                             int* __restrict__ cursor) {
    int i = blockIdx.x * blockDim.x + threadIdx.x;
    if (i < N_NODES) {
        int v = row_start[i] + block_sums[i / SCAN_TILE];
        row_start[i] = v;
        cursor[i] = v;
    }
    if (i == 0) row_start[N_NODES] = N_EDGES;
}

// ---- partition-affine CSR fill: 4 B col entries, NT streaming edge reads ----
// Block b: partition p = b % 8 (XCD p under round-robin dispatch), chunk b / 8.
// NT reads keep the partition's col slice + cursor resident in L2 so scatter
// writes to the same 64 B line merge before writeback.
__global__ void fill_part_kernel(const int* __restrict__ src, const int* __restrict__ dst,
                                 int* __restrict__ cursor, int* __restrict__ col) {
    int part = blockIdx.x & (NPART - 1);
    int chunk = blockIdx.x >> 3;
    int e = chunk * FILL_EPB + threadIdx.x * 4;
    int lo = part * PART_NODES;
    int hi = lo + PART_NODES;
    if (e + 3 < N_EDGES) {
        u64 slo = __builtin_nontemporal_load((const u64*)(src + e));
        u64 shi = __builtin_nontemporal_load((const u64*)(src + e) + 1);
        u64 dlo = __builtin_nontemporal_load((const u64*)(dst + e));
        u64 dhi = __builtin_nontemporal_load((const u64*)(dst + e) + 1);
        int s0 = (int)(slo & 0xffffffffu), s1 = (int)(slo >> 32);
        int s2 = (int)(shi & 0xffffffffu), s3 = (int)(shi >> 32);
        int d0 = (int)(dlo & 0xffffffffu), d1 = (int)(dlo >> 32);
        int d2 = (int)(dhi & 0xffffffffu), d3 = (int)(dhi >> 32);
        if (d0 >= lo && d0 < hi) col[atomicAdd(&cursor[d0], 1)] = s0;
        if (d1 >= lo && d1 < hi) col[atomicAdd(&cursor[d1], 1)] = s1;
        if (d2 >= lo && d2 < hi) col[atomicAdd(&cursor[d2], 1)] = s2;
        if (d3 >= lo && d3 < hi) col[atomicAdd(&cursor[d3], 1)] = s3;
    }
}

// ---- propagation: one wave per destination row, lane = embedding dim ----
// Pure unweighted sum of y (y = dinv*x): masked lane-parallel col fetch,
// one __shfl per edge, fp16 gathers, fp32 accumulate.
// Non-final: y_{l+1} = dinv^2 * acc. Final: out = 0.25*(emb + rdinv*(y1+y2) + dinv*acc).
template <bool FINAL>
__global__ void gather_kernel(const int* __restrict__ row_start, const int* __restrict__ col,
                              const float* __restrict__ dinv, const float* __restrict__ rdinv,
                              const f16* __restrict__ yin, f16* __restrict__ yout,
                              const float* __restrict__ emb,
                              const f16* __restrict__ y1, const f16* __restrict__ y2,
                              float* __restrict__ out) {
    unsigned int gid = blockIdx.x * blockDim.x + threadIdx.x;
    unsigned int row = gid >> 6;
    int d = (int)(gid & 63u);  // lane == embedding dim
    if (row >= N_NODES) return;
    int beg = row_start[row];
    int end = row_start[row + 1];
    float acc = 0.0f;
    for (int cb = beg; cb < end; cb += 64) {
        int idx = cb + d;
        int ci = 0;
        if (idx < end) ci = __builtin_nontemporal_load(&col[idx]);  // masked lane-parallel fetch
        int n = end - cb;
        if (n > 64) n = 64;
        int k = 0;
        for (; k + 3 < n; k += 4) {
            unsigned c0 = (unsigned)__shfl(ci, k);
            unsigned c1 = (unsigned)__shfl(ci, k + 1);
            unsigned c2 = (unsigned)__shfl(ci, k + 2);
            unsigned c3 = (unsigned)__shfl(ci, k + 3);
            float v0 = (float)yin[c0 * EMB + d];
            float v1 = (float)yin[c1 * EMB + d];
            float v2 = (float)yin[c2 * EMB + d];
            float v3 = (float)yin[c3 * EMB + d];
            acc += v0;
            acc += v1;
            acc += v2;
            acc += v3;
        }
        for (; k < n; ++k) {
            unsigned c = (unsigned)__shfl(ci, k);
            acc += (float)yin[c * EMB + d];
        }
    }
    float dv = dinv[row];
    unsigned int o = row * EMB + (unsigned)d;
    if (!FINAL) {
        __builtin_nontemporal_store((f16)(dv * dv * acc), &yout[o]);
    } else {
        float rv = rdinv[row];
        float r = 0.25f * (emb[o] + rv * ((float)y1[o] + (float)y2[o]) + dv * acc);
        __builtin_nontemporal_store(r, &out[o]);
    }
}

extern "C" void kernel_launch(void* const* d_in, const int* in_sizes, int n_in,
                              void* d_out, int out_size, void* d_ws, size_t ws_size,
                              hipStream_t stream) {
    const int*   edge = (const int*)d_in[0];   // (2, N_EDGES) row-major
    const int*   src  = edge;
    const int*   dst  = edge + N_EDGES;
    const float* emb  = (const float*)d_in[1]; // (N_NODES, 64) fp32
    float*       out  = (float*)d_out;

    // workspace carve (16B-aligned offsets), ~45 MB total
    char* ws = (char*)d_ws;
    size_t off = 0;
    int* deg       = (int*)(ws + off); off += 400000;  // reused as cursor
    int* row_start = (int*)(ws + off); off += 400016;
    int* bsums     = (int*)(ws + off); off += 512;
    float* dinv    = (float*)(ws + off); off += 400000;
    float* rdinv   = (float*)(ws + off); off += 400000;
    int* col       = (int*)(ws + off); off += (size_t)N_EDGES * 4;         // 5.12 MB
    f16* y0        = (f16*)(ws + off); off += (size_t)N_NODES * EMB * 2;   // 12.8 MB
    f16* y1        = (f16*)(ws + off); off += (size_t)N_NODES * EMB * 2;   // 12.8 MB
    f16* y2        = (f16*)(ws + off); off += (size_t)N_NODES * EMB * 2;   // 12.8 MB

    const int NB = (N_NODES + SCAN_TILE - 1) / SCAN_TILE;  // 98

    // ---- CSR build (once per call; reused by all 3 layers) ----
    hipMemsetAsync(deg, 0, (size_t)N_NODES * sizeof(int), stream);
    deg_kernel<<<(N_EDGES / 4 + 255) / 256, 256, 0, stream>>>(dst, deg);
    norm_kernel<<<(N_NODES + 255) / 256, 256, 0, stream>>>(deg, dinv, rdinv);
    y0_kernel<<<(N_NODES * EMB / 4 + 255) / 256, 256, 0, stream>>>(emb, dinv, y0);
    scan1_kernel<<<NB, 256, 0, stream>>>(deg, row_start, bsums);
    scan2_kernel<<<1, 128, 0, stream>>>(bsums, NB);
    scan3_kernel<<<(N_NODES + 255) / 256, 256, 0, stream>>>(row_start, bsums, deg /*cursor*/);
    fill_part_kernel<<<(N_EDGES / FILL_EPB) * NPART, 256, 0, stream>>>(src, dst,
                                                                      deg /*cursor*/, col);

    // ---- 3 propagation layers (pure y-sums), final fuses the 1/4-sum ----
    const unsigned int gthreads = (unsigned int)N_NODES * EMB;
    const int gblocks = (int)((gthreads + 255) / 256);
    gather_kernel<false><<<gblocks, 256, 0, stream>>>(row_start, col, dinv, rdinv,
                                                      y0, y1, emb, y1, y2, out);
    gather_kernel<false><<<gblocks, 256, 0, stream>>>(row_start, col, dinv, rdinv,
                                                      y1, y2, emb, y1, y2, out);
    gather_kernel<true><<<gblocks, 256, 0, stream>>>(row_start, col, dinv, rdinv,
                                                     y2, (f16*)0, emb, y1, y2, out);
}